// Round 1
// baseline (159.302 us; speedup 1.0000x reference)
//
#include <hip/hip_runtime.h>
#include <math.h>

#define DIM   2048
#define NEXP  64
#define TOPK  8
#define BM    64
#define BK    32
#define NT    512
#define LDK   (BK + 4)   // 36-float stride: 16B-aligned, conflict-free compute reads

__global__ void zero_counts_kernel(float* counts) {
    if (threadIdx.x < NEXP) counts[threadIdx.x] = 0.0f;
}

#define DOT4(a, b) ((a).x*(b).x + (a).y*(b).y + (a).z*(b).z + (a).w*(b).w)

__global__ __launch_bounds__(NT) void router_kernel(
    const float* __restrict__ x,
    const float* __restrict__ w,
    const float* __restrict__ bias,
    float* __restrict__ out,   // [M*8] scores | [M*8] indices(as f32) | [64] counts(as f32)
    int M)
{
    __shared__ float xs[BM][LDK];
    __shared__ float ws[NEXP][LDK];
    __shared__ float lg[BM][NEXP + 1];
    __shared__ int   hist[NEXP];

    const int tid  = threadIdx.x;
    const int row0 = blockIdx.x * BM;

    if (tid < NEXP) hist[tid] = 0;

    // compute-thread tile: 32 x 16 grid; each thread: 2 rows x 4 experts
    const int tr = tid >> 4;    // 0..31
    const int tc = tid & 15;    // 0..15

    // staging: each thread loads one float4 of x and one of w per K-step
    const int srow = tid >> 3;         // 0..63
    const int sc   = (tid & 7) * 4;    // 0,4,...,28

    const float* xg = x + (long)(row0 + srow) * DIM + sc;
    const float* wg = w + (long)srow * DIM + sc;

    float acc[2][4];
    #pragma unroll
    for (int i = 0; i < 2; ++i)
        #pragma unroll
        for (int j = 0; j < 4; ++j) acc[i][j] = 0.f;

    for (int k0 = 0; k0 < DIM; k0 += BK) {
        float4 xv = *(const float4*)(xg + k0);
        float4 wv = *(const float4*)(wg + k0);
        __syncthreads();   // previous tile fully consumed before overwrite
        *(float4*)&xs[srow][sc] = xv;
        *(float4*)&ws[srow][sc] = wv;
        __syncthreads();
        #pragma unroll
        for (int kk = 0; kk < BK; kk += 4) {
            float4 xa0 = *(const float4*)&xs[tr      ][kk];
            float4 xa1 = *(const float4*)&xs[tr + 32 ][kk];
            float4 wb0 = *(const float4*)&ws[tc      ][kk];
            float4 wb1 = *(const float4*)&ws[tc + 16 ][kk];
            float4 wb2 = *(const float4*)&ws[tc + 32 ][kk];
            float4 wb3 = *(const float4*)&ws[tc + 48 ][kk];
            acc[0][0] += DOT4(xa0, wb0);
            acc[0][1] += DOT4(xa0, wb1);
            acc[0][2] += DOT4(xa0, wb2);
            acc[0][3] += DOT4(xa0, wb3);
            acc[1][0] += DOT4(xa1, wb0);
            acc[1][1] += DOT4(xa1, wb1);
            acc[1][2] += DOT4(xa1, wb2);
            acc[1][3] += DOT4(xa1, wb3);
        }
    }

    __syncthreads();
    #pragma unroll
    for (int i = 0; i < 2; ++i)
        #pragma unroll
        for (int j = 0; j < 4; ++j)
            lg[tr + 32*i][tc + 16*j] = acc[i][j] + bias[tc + 16*j];
    __syncthreads();

    const int wave = tid >> 6;   // 0..7
    const int lane = tid & 63;

    float* out_scores = out;
    float* out_idx    = out + (long)M * TOPK;
    float* out_counts = out + (long)2 * M * TOPK;

    // each wave handles 8 rows
    for (int r8 = 0; r8 < 8; ++r8) {
        const int row = wave * 8 + r8;
        float vm = lg[row][lane];    // lane e holds logit for expert e
        float vals[TOPK];
        int   ids[TOPK];
        #pragma unroll
        for (int k = 0; k < TOPK; ++k) {
            float mv = vm;
            int   mi = lane;
            #pragma unroll
            for (int off = 32; off > 0; off >>= 1) {
                float ov = __shfl_xor(mv, off);
                int   oi = __shfl_xor(mi, off);
                if (ov > mv || (ov == mv && oi < mi)) { mv = ov; mi = oi; }
            }
            vals[k] = mv; ids[k] = mi;
            if (lane == mi) { vm = -INFINITY; atomicAdd(&hist[mi], 1); }
        }
        if (lane == 0) {
            const float m = vals[0];
            float e[TOPK];
            float ssum = 0.f;
            #pragma unroll
            for (int k = 0; k < TOPK; ++k) { e[k] = expf(vals[k] - m); ssum += e[k]; }
            const float inv = 1.0f / ssum;
            const long base = (long)(row0 + row) * TOPK;
            #pragma unroll
            for (int k = 0; k < TOPK; ++k) {
                out_scores[base + k] = e[k] * inv;
                out_idx[base + k]    = (float)ids[k];
            }
        }
    }

    __syncthreads();
    if (tid < NEXP) atomicAdd(&out_counts[tid], (float)hist[tid]);
}

extern "C" void kernel_launch(void* const* d_in, const int* in_sizes, int n_in,
                              void* d_out, int out_size, void* d_ws, size_t ws_size,
                              hipStream_t stream) {
    const float* x    = (const float*)d_in[0];
    const float* w    = (const float*)d_in[1];
    const float* bias = (const float*)d_in[2];
    float* out = (float*)d_out;
    const int M = in_sizes[0] / DIM;   // 4*4096 = 16384 rows

    float* out_counts = out + (long)2 * M * TOPK;
    zero_counts_kernel<<<1, 64, 0, stream>>>(out_counts);
    router_kernel<<<M / BM, NT, 0, stream>>>(x, w, bias, out, M);
}

// Round 2
// 95.688 us; speedup vs baseline: 1.6648x; 1.6648x over previous
//
#include <hip/hip_runtime.h>
#include <math.h>

#define DIM   2048
#define NEXP  64
#define TOPK  8
#define BM    64
#define NT    512
#define BK    32
#define KHALF 1024
#define ITERS (KHALF / BK)   // 32
#define LROW  40             // ushort stride per LDS row = 80 B (= 5*16B, keeps b128 alignment)

typedef __attribute__((ext_vector_type(8)))  short  bf16x8;
typedef __attribute__((ext_vector_type(16))) float  f32x16;
typedef __attribute__((ext_vector_type(4)))  unsigned short u16x4;

__global__ void zero_counts_kernel(float* counts) {
    if (threadIdx.x < NEXP) counts[threadIdx.x] = 0.0f;
}

__device__ inline unsigned short f2bf(float f) {
    unsigned int u = __float_as_uint(f);
    unsigned int r = (u + 0x7FFFu + ((u >> 16) & 1u)) >> 16;   // RNE
    return (unsigned short)r;
}
__device__ inline float bf2f(unsigned short h) {
    return __uint_as_float(((unsigned int)h) << 16);
}

// exact 3-way bf16 split: v ~= hi + mid + lo  (residuals exact in fp32)
__device__ inline void split3(float v, unsigned short& h, unsigned short& m, unsigned short& l) {
    h = f2bf(v);
    float r1 = v - bf2f(h);
    m = f2bf(r1);
    float r2 = r1 - bf2f(m);
    l = f2bf(r2);
}

__device__ inline void split3_4(const float4 v, u16x4& h, u16x4& m, u16x4& l) {
    unsigned short hh[4], mm[4], ll[4];
    const float vv[4] = {v.x, v.y, v.z, v.w};
    #pragma unroll
    for (int i = 0; i < 4; ++i) split3(vv[i], hh[i], mm[i], ll[i]);
    h = (u16x4){hh[0], hh[1], hh[2], hh[3]};
    m = (u16x4){mm[0], mm[1], mm[2], mm[3]};
    l = (u16x4){ll[0], ll[1], ll[2], ll[3]};
}

#define MFMA(A, B, C) __builtin_amdgcn_mfma_f32_32x32x16_bf16(A, B, C, 0, 0, 0)

__global__ __launch_bounds__(NT, 2) void router_kernel(
    const float* __restrict__ x,
    const float* __restrict__ w,
    const float* __restrict__ bias,
    float* __restrict__ out,   // [M*8] scores | [M*8] indices(f32) | [64] counts(f32)
    int M)
{
    __shared__ __align__(16) unsigned short xs[2][3][BM][LROW];
    __shared__ __align__(16) unsigned short ws[2][3][NEXP][LROW];
    __shared__ float lg[BM][NEXP + 1];
    __shared__ int   hist[NEXP];

    const int tid  = threadIdx.x;
    const int row0 = blockIdx.x * BM;
    if (tid < NEXP) hist[tid] = 0;

    // ---------- staging role: each thread owns one float4 per (array, k-group) ----------
    const int srow = tid >> 3;            // 0..63 (x row / w expert)
    const int sc4  = (tid & 7) * 4;       // k-local float offset 0,4,...,28
    const int sgi  = (sc4 >> 3) ^ ((srow >> 3) & 1);   // XOR-swizzled 16B granule
    const int sbyte = sgi * 16 + (sc4 & 7) * 2;

    const float* xg = x + (size_t)(row0 + srow) * DIM + sc4;
    const float* wg = w + (size_t)srow * DIM + sc4;

    char* xrow[2][3]; char* wrow[2][3];
    #pragma unroll
    for (int g = 0; g < 2; ++g)
        #pragma unroll
        for (int s = 0; s < 3; ++s) {
            xrow[g][s] = (char*)&xs[g][s][srow][0] + sbyte;
            wrow[g][s] = (char*)&ws[g][s][srow][0] + sbyte;
        }

    // ---------- compute role: 8 waves = (2x2 tiles) x (split-K 2) ----------
    const int wv   = tid >> 6;
    const int lane = tid & 63;
    const int g    = wv >> 2;             // K-group
    const int tile = wv & 3;
    const int trow = (tile >> 1) * 32;
    const int tcol = (tile & 1) * 32;
    const int lrow = lane & 31;
    const int kh   = lane >> 5;           // k-half within K16
    const int ar   = trow + lrow;         // x row in block
    const int bc   = tcol + lrow;         // expert col
    const int xa   = (ar >> 3) & 1;
    const int xb   = (bc >> 3) & 1;

    const char* xbaseS[3]; const char* wbaseS[3];
    #pragma unroll
    for (int s = 0; s < 3; ++s) {
        xbaseS[s] = (const char*)&xs[g][s][ar][0];
        wbaseS[s] = (const char*)&ws[g][s][bc][0];
    }
    const float biasv = bias[tcol + lrow];

    f32x16 acc = {};

    float4 cx0 = *(const float4*)(xg);
    float4 cx1 = *(const float4*)(xg + KHALF);
    float4 cw0 = *(const float4*)(wg);
    float4 cw1 = *(const float4*)(wg + KHALF);
    float4 nx0, nx1, nw0, nw1;

    #pragma unroll 2
    for (int t = 0; t < ITERS; ++t) {
        if (t + 1 < ITERS) {
            const int o = (t + 1) * BK;
            nx0 = *(const float4*)(xg + o);
            nx1 = *(const float4*)(xg + KHALF + o);
            nw0 = *(const float4*)(wg + o);
            nw1 = *(const float4*)(wg + KHALF + o);
        }
        __syncthreads();                    // previous tile fully consumed
        {
            u16x4 h, m, l;
            split3_4(cx0, h, m, l);
            *(u16x4*)(xrow[0][0]) = h; *(u16x4*)(xrow[0][1]) = m; *(u16x4*)(xrow[0][2]) = l;
            split3_4(cx1, h, m, l);
            *(u16x4*)(xrow[1][0]) = h; *(u16x4*)(xrow[1][1]) = m; *(u16x4*)(xrow[1][2]) = l;
            split3_4(cw0, h, m, l);
            *(u16x4*)(wrow[0][0]) = h; *(u16x4*)(wrow[0][1]) = m; *(u16x4*)(wrow[0][2]) = l;
            split3_4(cw1, h, m, l);
            *(u16x4*)(wrow[1][0]) = h; *(u16x4*)(wrow[1][1]) = m; *(u16x4*)(wrow[1][2]) = l;
        }
        __syncthreads();                    // tile ready
        #pragma unroll
        for (int ks = 0; ks < 2; ++ks) {
            const int sa = (((ks << 1) + kh) ^ xa) << 4;
            const int sb = (((ks << 1) + kh) ^ xb) << 4;
            bf16x8 ah = *(const bf16x8*)(xbaseS[0] + sa);
            bf16x8 am = *(const bf16x8*)(xbaseS[1] + sa);
            bf16x8 al = *(const bf16x8*)(xbaseS[2] + sa);
            bf16x8 bh = *(const bf16x8*)(wbaseS[0] + sb);
            bf16x8 bm = *(const bf16x8*)(wbaseS[1] + sb);
            bf16x8 bl = *(const bf16x8*)(wbaseS[2] + sb);
            acc = MFMA(ah, bh, acc);
            acc = MFMA(ah, bm, acc);
            acc = MFMA(am, bh, acc);
            acc = MFMA(ah, bl, acc);
            acc = MFMA(al, bh, acc);
            acc = MFMA(am, bm, acc);
        }
        cx0 = nx0; cx1 = nx1; cw0 = nw0; cw1 = nw1;
    }

    // ---------- split-K reduce + bias into lg ----------
    __syncthreads();
    if (g == 0) {
        #pragma unroll
        for (int r = 0; r < 16; ++r) {
            const int rr = (r & 3) + 8 * (r >> 2) + 4 * kh;   // verified C-layout (m74/m101)
            lg[trow + rr][tcol + lrow] = acc[r];
        }
    }
    __syncthreads();
    if (g == 1) {
        #pragma unroll
        for (int r = 0; r < 16; ++r) {
            const int rr = (r & 3) + 8 * (r >> 2) + 4 * kh;
            lg[trow + rr][tcol + lrow] += acc[r] + biasv;
        }
    }
    __syncthreads();

    // ---------- top-k + softmax + histogram (unchanged, verified) ----------
    float* out_scores = out;
    float* out_idx    = out + (size_t)M * TOPK;
    float* out_counts = out + (size_t)2 * M * TOPK;

    for (int r8 = 0; r8 < 8; ++r8) {
        const int row = wv * 8 + r8;
        float vm = lg[row][lane];
        float vals[TOPK];
        int   ids[TOPK];
        #pragma unroll
        for (int k = 0; k < TOPK; ++k) {
            float mv = vm;
            int   mi = lane;
            #pragma unroll
            for (int off = 32; off > 0; off >>= 1) {
                float ov = __shfl_xor(mv, off);
                int   oi = __shfl_xor(mi, off);
                if (ov > mv || (ov == mv && oi < mi)) { mv = ov; mi = oi; }
            }
            vals[k] = mv; ids[k] = mi;
            if (lane == mi) { vm = -INFINITY; atomicAdd(&hist[mi], 1); }
        }
        if (lane == 0) {
            const float m = vals[0];
            float e[TOPK];
            float ssum = 0.f;
            #pragma unroll
            for (int k = 0; k < TOPK; ++k) { e[k] = expf(vals[k] - m); ssum += e[k]; }
            const float inv = 1.0f / ssum;
            const size_t base = (size_t)(row0 + row) * TOPK;
            #pragma unroll
            for (int k = 0; k < TOPK; ++k) {
                out_scores[base + k] = e[k] * inv;
                out_idx[base + k]    = (float)ids[k];
            }
        }
    }

    __syncthreads();
    if (tid < NEXP) atomicAdd(&out_counts[tid], (float)hist[tid]);
}

extern "C" void kernel_launch(void* const* d_in, const int* in_sizes, int n_in,
                              void* d_out, int out_size, void* d_ws, size_t ws_size,
                              hipStream_t stream) {
    const float* x    = (const float*)d_in[0];
    const float* w    = (const float*)d_in[1];
    const float* bias = (const float*)d_in[2];
    float* out = (float*)d_out;
    const int M = in_sizes[0] / DIM;   // 16384 rows

    float* out_counts = out + (size_t)2 * M * TOPK;
    zero_counts_kernel<<<1, 64, 0, stream>>>(out_counts);
    router_kernel<<<M / BM, NT, 0, stream>>>(x, w, bias, out, M);
}

// Round 3
// 81.961 us; speedup vs baseline: 1.9436x; 1.1675x over previous
//
#include <hip/hip_runtime.h>
#include <math.h>

#define DIM   2048
#define NEXP  64
#define TOPK  8
#define ROWS  32            // rows per block
#define NT    512           // 8 waves: split-K-8
#define KW    (DIM / 8)     // 256 k per wave
#define STEPS (KW / 16)     // 16 MFMA K16-steps per wave

typedef __attribute__((ext_vector_type(8)))  short bf16x8;
typedef __attribute__((ext_vector_type(16))) float f32x16;

#define MFMA(A, B, C) __builtin_amdgcn_mfma_f32_32x32x16_bf16(A, B, C, 0, 0, 0)
#define AS_BF(v) (*(const bf16x8*)&(v))

// pack two floats -> two RNE bf16 in one uint (low = a, high = b)
__device__ inline unsigned int bfpack(float a, float b) {
    unsigned int ua = __float_as_uint(a), ub = __float_as_uint(b);
    unsigned int lo = (ua + 0x7FFFu + ((ua >> 16) & 1u)) >> 16;
    unsigned int hi = (ub + 0x7FFFu + ((ub >> 16) & 1u)) & 0xFFFF0000u;
    return hi | lo;
}

// exact 2-term split of a float pair: v ~= h + m (+ dropped ~2^-18 tail)
__device__ inline void split2pair(float a, float b, unsigned int& h, unsigned int& m) {
    h = bfpack(a, b);
    float ra = a - __uint_as_float(h << 16);
    float rb = b - __uint_as_float(h & 0xFFFF0000u);
    m = bfpack(ra, rb);
}

// w [64][2048] f32 -> wpack[(e*256 + k8)] = {h[4] uints, m[4] uints} (32 B per k8-group)
__global__ __launch_bounds__(256) void prep_kernel(const float* __restrict__ w,
                                                   unsigned int* __restrict__ wpack,
                                                   float* __restrict__ counts) {
    const int t = blockIdx.x * 256 + threadIdx.x;   // 16384 threads, 8 floats each
    if (blockIdx.x == 0 && threadIdx.x < NEXP) counts[threadIdx.x] = 0.0f;
    const float4 v0 = *(const float4*)(w + (size_t)t * 8);
    const float4 v1 = *(const float4*)(w + (size_t)t * 8 + 4);
    unsigned int h[4], m[4];
    split2pair(v0.x, v0.y, h[0], m[0]);
    split2pair(v0.z, v0.w, h[1], m[1]);
    split2pair(v1.x, v1.y, h[2], m[2]);
    split2pair(v1.z, v1.w, h[3], m[3]);
    uint4* dst = (uint4*)(wpack + (size_t)t * 8);
    dst[0] = (uint4){h[0], h[1], h[2], h[3]};
    dst[1] = (uint4){m[0], m[1], m[2], m[3]};
}

__global__ __launch_bounds__(NT, 4) void router_kernel(
    const float* __restrict__ x,
    const unsigned int* __restrict__ wpack,
    const float* __restrict__ bias,
    float* __restrict__ out,   // [M*8] scores | [M*8] idx(f32) | [64] counts(f32)
    int M)
{
    __shared__ float lg[8][ROWS][NEXP + 2];
    __shared__ int   hist[NEXP];

    const int tid  = threadIdx.x;
    const int wv   = tid >> 6;          // 0..7 : K-slice
    const int lane = tid & 63;
    const int lrow = lane & 31;
    const int kh   = lane >> 5;         // k-half within K16
    const int row0 = blockIdx.x * ROWS;
    if (tid < NEXP) hist[tid] = 0;

    // x: lane reads row (row0+lrow), 8 consecutive floats at k = wv*KW + t*16 + kh*8
    const float* xp = x + (size_t)(row0 + lrow) * DIM + wv * KW + kh * 8;
    // w: expert e fragment at k8 = k/8 lives at uint index (e*256 + k8)*8 ; h at +0, m at +4
    const unsigned int* wb0 = wpack + ((size_t)lrow * (DIM / 8) + wv * (KW / 8) + kh) * 8;
    const unsigned int* wb1 = wb0 + (size_t)32 * (DIM / 8) * 8;

    f32x16 acc0 = {}, acc1 = {};

    #pragma unroll 4
    for (int t = 0; t < STEPS; ++t) {
        const float4 xv0 = *(const float4*)(xp + t * 16);
        const float4 xv1 = *(const float4*)(xp + t * 16 + 4);
        const uint4 b0h = *(const uint4*)(wb0 + (size_t)t * 16);
        const uint4 b0m = *(const uint4*)(wb0 + (size_t)t * 16 + 4);
        const uint4 b1h = *(const uint4*)(wb1 + (size_t)t * 16);
        const uint4 b1m = *(const uint4*)(wb1 + (size_t)t * 16 + 4);

        unsigned int ah[4], am[4];
        split2pair(xv0.x, xv0.y, ah[0], am[0]);
        split2pair(xv0.z, xv0.w, ah[1], am[1]);
        split2pair(xv1.x, xv1.y, ah[2], am[2]);
        split2pair(xv1.z, xv1.w, ah[3], am[3]);
        const uint4 ahv = (uint4){ah[0], ah[1], ah[2], ah[3]};
        const uint4 amv = (uint4){am[0], am[1], am[2], am[3]};

        // 3-term fp32 emulation: hh + mh + hm
        acc0 = MFMA(AS_BF(ahv), AS_BF(b0h), acc0);
        acc1 = MFMA(AS_BF(ahv), AS_BF(b1h), acc1);
        acc0 = MFMA(AS_BF(amv), AS_BF(b0h), acc0);
        acc1 = MFMA(AS_BF(amv), AS_BF(b1h), acc1);
        acc0 = MFMA(AS_BF(ahv), AS_BF(b0m), acc0);
        acc1 = MFMA(AS_BF(ahv), AS_BF(b1m), acc1);
    }

    // split-K partials to LDS
    #pragma unroll
    for (int r = 0; r < 16; ++r) {
        const int rr = (r & 3) + 8 * (r >> 2) + 4 * kh;   // verified C-layout (m74/m101)
        lg[wv][rr][lrow]      = acc0[r];
        lg[wv][rr][32 + lrow] = acc1[r];
    }
    __syncthreads();

    float* out_scores = out;
    float* out_idx    = out + (size_t)M * TOPK;
    float* out_counts = out + (size_t)2 * M * TOPK;

    // each wave: 4 rows; lane = expert
    #pragma unroll
    for (int i = 0; i < 4; ++i) {
        const int row = wv * 4 + i;
        float vm = bias[lane];
        #pragma unroll
        for (int p = 0; p < 8; ++p) vm += lg[p][row][lane];

        float vals[TOPK];
        int   ids[TOPK];
        #pragma unroll
        for (int k = 0; k < TOPK; ++k) {
            float mv = vm;
            int   mi = lane;
            #pragma unroll
            for (int off = 32; off > 0; off >>= 1) {
                float ov = __shfl_xor(mv, off);
                int   oi = __shfl_xor(mi, off);
                if (ov > mv || (ov == mv && oi < mi)) { mv = ov; mi = oi; }
            }
            vals[k] = mv; ids[k] = mi;
            if (lane == mi) { vm = -INFINITY; atomicAdd(&hist[mi], 1); }
        }
        if (lane == 0) {
            const float m = vals[0];
            float e[TOPK];
            float ssum = 0.f;
            #pragma unroll
            for (int k = 0; k < TOPK; ++k) { e[k] = expf(vals[k] - m); ssum += e[k]; }
            const float inv = 1.0f / ssum;
            const size_t base = (size_t)(row0 + row) * TOPK;
            #pragma unroll
            for (int k = 0; k < TOPK; ++k) {
                out_scores[base + k] = e[k] * inv;
                out_idx[base + k]    = (float)ids[k];
            }
        }
    }

    __syncthreads();
    if (tid < NEXP) atomicAdd(&out_counts[tid], (float)hist[tid]);
}

extern "C" void kernel_launch(void* const* d_in, const int* in_sizes, int n_in,
                              void* d_out, int out_size, void* d_ws, size_t ws_size,
                              hipStream_t stream) {
    const float* x    = (const float*)d_in[0];
    const float* w    = (const float*)d_in[1];
    const float* bias = (const float*)d_in[2];
    float* out = (float*)d_out;
    const int M = in_sizes[0] / DIM;   // 16384 rows

    unsigned int* wpack = (unsigned int*)d_ws;               // 512 KB
    float* out_counts = out + (size_t)2 * M * TOPK;

    prep_kernel<<<(NEXP * DIM / 8) / 256, 256, 0, stream>>>(w, wpack, out_counts);
    router_kernel<<<M / ROWS, NT, 0, stream>>>(x, wpack, bias, out, M);
}